// Round 1
// baseline (178.542 us; speedup 1.0000x reference)
//
#include <hip/hip_runtime.h>

// SSIM (skimage default): 7x7 uniform filter, valid crop (pad=3), sample cov.
// Images: 4096x4096 fp32, output region 4090x4090, result = mean(S) scalar.

#define W_IMG   4096
#define H_IMG   4096
#define OW      4090
#define OH      4090
#define ROWS    32            // output rows per block strip
#define NTHR    256           // threads per block
#define CPB     512           // output columns per block (2 per thread)

__device__ __forceinline__ void hsums(const float* __restrict__ pO,
                                      const float* __restrict__ pT,
                                      float h[10])
{
    // load 8 consecutive floats of each image (8B-aligned: col0 is even)
    float2 a0 = *(const float2*)(pO + 0);
    float2 a1 = *(const float2*)(pO + 2);
    float2 a2 = *(const float2*)(pO + 4);
    float2 a3 = *(const float2*)(pO + 6);
    float2 b0 = *(const float2*)(pT + 0);
    float2 b1 = *(const float2*)(pT + 2);
    float2 b2 = *(const float2*)(pT + 4);
    float2 b3 = *(const float2*)(pT + 6);
    float o0=a0.x,o1=a0.y,o2=a1.x,o3=a1.y,o4=a2.x,o5=a2.y,o6=a3.x,o7=a3.y;
    float t0=b0.x,t1=b0.y,t2=b1.x,t3=b1.y,t4=b2.x,t5=b2.y,t6=b3.x,t7=b3.y;

    float so  = ((o0+o1)+(o2+o3)) + ((o4+o5)+o6);
    float st  = ((t0+t1)+(t2+t3)) + ((t4+t5)+t6);
    float soo = fmaf(o6,o6, fmaf(o5,o5, fmaf(o4,o4, fmaf(o3,o3, fmaf(o2,o2, fmaf(o1,o1, o0*o0))))));
    float stt = fmaf(t6,t6, fmaf(t5,t5, fmaf(t4,t4, fmaf(t3,t3, fmaf(t2,t2, fmaf(t1,t1, t0*t0))))));
    float sot = fmaf(o6,t6, fmaf(o5,t5, fmaf(o4,t4, fmaf(o3,t3, fmaf(o2,t2, fmaf(o1,t1, o0*t0))))));

    h[0] = so;   h[1] = so  - o0    + o7;
    h[2] = st;   h[3] = st  - t0    + t7;
    h[4] = soo;  h[5] = soo - o0*o0 + o7*o7;
    h[6] = stt;  h[7] = stt - t0*t0 + t7*t7;
    h[8] = sot;  h[9] = sot - o0*t0 + o7*t7;
}

__device__ __forceinline__ float ssim_from(const float v[10], int px)
{
    const float m    = 1.0f / 49.0f;
    const float covn = 49.0f / 48.0f;
    const float C1   = 4.0e-4f;   // (0.01*2)^2
    const float C2   = 3.6e-3f;   // (0.03*2)^2
    float so  = v[0+px], st  = v[2+px];
    float soo = v[4+px], stt = v[6+px], sot = v[8+px];
    float ux  = so*m,  uy  = st*m;
    float uxx = soo*m, uyy = stt*m, uxy = sot*m;
    float vx  = covn*(uxx - ux*ux);
    float vy  = covn*(uyy - uy*uy);
    float vxy = covn*(uxy - ux*uy);
    float A1  = 2.0f*ux*uy + C1;
    float A2  = 2.0f*vxy + C2;
    float B1  = (ux*ux + uy*uy) + C1;
    float B2  = (vx + vy) + C2;
    float num = A1*A2;
    float den = B1*B2;
    return num * __builtin_amdgcn_rcpf(den);   // ~1 ulp, far within tolerance
}

__global__ __launch_bounds__(NTHR, 3)
void ssim_main(const float* __restrict__ O, const float* __restrict__ T,
               float* __restrict__ accp)
{
    const int t  = threadIdx.x;
    const int c0 = blockIdx.x * CPB + 2*t;     // first of the 2 output cols
    const int r0 = blockIdx.y * ROWS;          // first output row of strip
    const int rows_in = min(ROWS, OH - r0);

    float acc = 0.0f;

    if (c0 < OW) {  // c0 even, OW even -> both pixels valid together
        const float* baseO = O + (size_t)r0 * W_IMG + c0;
        const float* baseT = T + (size_t)r0 * W_IMG + c0;

        float ring[7][10];   // 7-row delay line of horizontal sums (regs)
        float v[10];         // running vertical sums over the 7-row window
        #pragma unroll
        for (int q = 0; q < 10; q++) v[q] = 0.0f;

        // warm-up: input rows 0..5
        #pragma unroll
        for (int i = 0; i < 6; i++) {
            float h[10];
            hsums(baseO + (size_t)i * W_IMG, baseT + (size_t)i * W_IMG, h);
            #pragma unroll
            for (int q = 0; q < 10; q++) { v[q] += h[q]; ring[i][q] = h[q]; }
        }

        // steady: output row j (input row i = j+6); chunked by 7 so ring
        // slot indices are compile-time constants (stays in VGPRs).
        for (int jb = 0; jb < ROWS; jb += 7) {
            #pragma unroll
            for (int u = 0; u < 7; u++) {
                const int j = jb + u;
                if (j < rows_in) {
                    const int i = j + 6;
                    float h[10];
                    hsums(baseO + (size_t)i * W_IMG,
                          baseT + (size_t)i * W_IMG, h);
                    #pragma unroll
                    for (int q = 0; q < 10; q++) v[q] += h[q];
                    // window now covers rows [j, j+6]
                    acc += ssim_from(v, 0);
                    acc += ssim_from(v, 1);
                    // drop row i-6 (slot (i+1)%7 == u), store row i (slot i%7)
                    #pragma unroll
                    for (int q = 0; q < 10; q++) {
                        v[q] -= ring[u][q];
                        ring[(u + 6) % 7][q] = h[q];
                    }
                }
            }
        }
    }

    // wave(64) shuffle reduction
    #pragma unroll
    for (int off = 32; off; off >>= 1) acc += __shfl_down(acc, off);

    __shared__ float wpart[NTHR / 64];
    if ((t & 63) == 0) wpart[t >> 6] = acc;
    __syncthreads();
    if (t == 0) {
        float s = 0.0f;
        #pragma unroll
        for (int w = 0; w < NTHR / 64; w++) s += wpart[w];
        atomicAdd(accp, s);   // one atomic per block (1024 total)
    }
}

__global__ void ssim_final(const float* __restrict__ accp, float* __restrict__ out)
{
    out[0] = accp[0] * (float)(1.0 / ((double)OW * (double)OH));
}

extern "C" void kernel_launch(void* const* d_in, const int* in_sizes, int n_in,
                              void* d_out, int out_size, void* d_ws, size_t ws_size,
                              hipStream_t stream)
{
    const float* O = (const float*)d_in[0];
    const float* T = (const float*)d_in[1];
    float* out = (float*)d_out;
    float* acc = (float*)d_ws;

    hipMemsetAsync(acc, 0, sizeof(float), stream);   // ws is re-poisoned to 0xAA

    dim3 grid((OW + CPB - 1) / CPB, (OH + ROWS - 1) / ROWS);  // (8, 128)
    ssim_main<<<grid, NTHR, 0, stream>>>(O, T, acc);
    ssim_final<<<1, 1, 0, stream>>>(acc, out);
}